// Round 1
// baseline (2179.226 us; speedup 1.0000x reference)
//
#include <hip/hip_runtime.h>
#include <hip/hip_bf16.h>

typedef __hip_bfloat16 bf16;
typedef __attribute__((ext_vector_type(8))) short short8;
typedef __attribute__((ext_vector_type(4))) float float4v;

// ---------------- workspace layout (bytes) ----------------
#define SZ_XB   (32ull*1024*512*2)      // [B][1024][512] bf16
#define SZ_CAT  (32ull*1024*1024*2)     // [B][1024][1024] bf16
#define SZ_H    (32ull*1024*256*2)      // [B][1024][256] bf16
#define SZ_WTOW (2ull*3*512*512*2)      // per tower: 2 layers x [3][512][512] bf16
#define SZ_WMIX (512ull*1024*2)
#define SZ_WIOU (3ull*256*512*2)

#define OFF_XB   0ull
#define OFF_TMP  (OFF_XB + SZ_XB)
#define OFF_CAT  (OFF_TMP + SZ_XB)
#define OFF_H    (OFF_CAT + SZ_CAT)
#define OFF_WCLS (OFF_H + SZ_H)
#define OFF_WBOX (OFF_WCLS + SZ_WTOW)
#define OFF_WMIX (OFF_WBOX + SZ_WTOW)
#define OFF_WIOU (OFF_WMIX + SZ_WMIX)
#define OFF_AFF  (OFF_WIOU + SZ_WIOU)

// ---------------- prep kernels ----------------
// [Co][Ci][K] fp32 -> [K][Co][Ci] bf16
__global__ void wtrans(const float* __restrict__ w, bf16* __restrict__ o,
                       int Co, int Ci, int K) {
    long long idx = (long long)blockIdx.x * 256 + threadIdx.x;
    long long n = (long long)Co * Ci * K;
    if (idx >= n) return;
    int ci = (int)(idx % Ci);
    long long r = idx / Ci;
    int co = (int)(r % Co);
    int k  = (int)(r / Co);
    o[idx] = __float2bfloat16(w[((long long)co * Ci + ci) * K + k]);
}

// BN fold: scale = g*rsqrt(v+eps); bias = cb*scale + beta - m*scale
__global__ void mkaff(const float* __restrict__ g, const float* __restrict__ beta,
                      const float* __restrict__ m, const float* __restrict__ v,
                      const float* __restrict__ cb, float* __restrict__ out, int C) {
    int i = blockIdx.x * 256 + threadIdx.x;
    if (i >= C) return;
    float s = g[i] * rsqrtf(v[i] + 1e-5f);
    out[i] = s;
    out[C + i] = cb[i] * s + beta[i] - m[i] * s;
}

// x [B][512][T] fp32 -> xb [B][T][512] bf16
__global__ void transpose_cvt(const float* __restrict__ x, bf16* __restrict__ xb, int T) {
    __shared__ float tile[32][33];
    int t0 = blockIdx.x * 32, c0 = blockIdx.y * 32, b = blockIdx.z;
    const float* xp = x + ((size_t)b * 512 + c0) * T + t0;
    for (int i = 0; i < 4; i++) {
        int c = threadIdx.y + i * 8;
        tile[c][threadIdx.x] = xp[(size_t)c * T + threadIdx.x];
    }
    __syncthreads();
    bf16* yp = xb + ((size_t)b * T + t0) * 512 + c0;
    for (int i = 0; i < 4; i++) {
        int t = threadIdx.y + i * 8;
        yp[(size_t)t * 512 + threadIdx.x] = __float2bfloat16(tile[threadIdx.x][t]);
    }
}

// locations
__global__ void locs_k(float* __restrict__ out) {
    int i = blockIdx.x * 256 + threadIdx.x;
    if (i < 1024)      out[i] = (float)i + 0.5f;
    else if (i < 1536) out[i] = (float)(i - 1024) * 2.0f + 1.0f;
    else if (i < 1792) out[i] = (float)(i - 1536) * 4.0f + 2.0f;
}

// ---------------- main MFMA conv (k=3 pad=1 or k=1 pad=0) + BN + ReLU ----------------
// X: [B][T][xstride] bf16 ; Wt: [taps][CoutTot][Cin] bf16 ; Y: [B][T][ystride] bf16 at col ycol
// grid: (CoutTot/128, T/128, B), block 256
__global__ __launch_bounds__(256) void conv_mfma(
    const bf16* __restrict__ X, int T, int Cin, int xstride,
    const bf16* __restrict__ Wt, int taps, int CoutTot,
    const float* __restrict__ aff,
    bf16* __restrict__ Y, int ystride, int ycol, int relu)
{
    __shared__ short Alds[130 * 40];      // 130 rows x 32 ci, stride 40 (80B, conflict-free)
    __shared__ short Wlds[3 * 128 * 40];  // [tap][128 co][32 ci]

    int co0 = blockIdx.x * 128, t0 = blockIdx.y * 128, b = blockIdx.z;
    int tid = threadIdx.x;
    int lane = tid & 63, wv = tid >> 6;
    int wm = wv >> 1, wn = wv & 1;
    int quad = lane >> 4, l15 = lane & 15;

    float4v acc[4][4] = {};

    int kIters = Cin >> 5;  // 32 ci per iteration
    int arows = (taps == 3) ? 130 : 128;
    int halo = (taps == 3) ? 1 : 0;

    for (int kk = 0; kk < kIters; kk++) {
        int ci0 = kk << 5;
        if (kk) __syncthreads();
        // stage A (X patches): rows t0-halo .. t0-halo+arows
        for (int idx = tid; idx < arows * 4; idx += 256) {
            int r = idx >> 2, part = idx & 3;
            int tg = t0 + r - halo;
            short8 v = {0, 0, 0, 0, 0, 0, 0, 0};
            if (tg >= 0 && tg < T)
                v = *(const short8*)(X + ((size_t)b * T + tg) * xstride + ci0 + part * 8);
            *(short8*)&Alds[r * 40 + part * 8] = v;
        }
        // stage W: [tap][128 co][32 ci]
        for (int idx = tid; idx < taps * 512; idx += 256) {
            int tap = idx >> 9, rem = idx & 511;
            int row = rem >> 2, part = rem & 3;
            short8 v = *(const short8*)(Wt + ((size_t)tap * CoutTot + co0 + row) * Cin + ci0 + part * 8);
            *(short8*)&Wlds[tap * 5120 + row * 40 + part * 8] = v;
        }
        __syncthreads();

        for (int tap = 0; tap < taps; tap++) {
            int rowoff = (taps == 3) ? tap : 0;
            short8 af[4], bfr[4];
#pragma unroll
            for (int mi = 0; mi < 4; mi++)
                af[mi] = *(short8*)&Alds[(wm * 64 + mi * 16 + l15 + rowoff) * 40 + quad * 8];
#pragma unroll
            for (int ni = 0; ni < 4; ni++)
                bfr[ni] = *(short8*)&Wlds[tap * 5120 + (wn * 64 + ni * 16 + l15) * 40 + quad * 8];
#pragma unroll
            for (int mi = 0; mi < 4; mi++)
#pragma unroll
                for (int ni = 0; ni < 4; ni++)
                    acc[mi][ni] = __builtin_amdgcn_mfma_f32_16x16x32_bf16(
                        af[mi], bfr[ni], acc[mi][ni], 0, 0, 0);
        }
    }

    // epilogue: affine + relu + bf16 store
#pragma unroll
    for (int ni = 0; ni < 4; ni++) {
        int col = co0 + wn * 64 + ni * 16 + l15;
        float s = 1.f, bb = 0.f;
        if (aff) { s = aff[col]; bb = aff[CoutTot + col]; }
#pragma unroll
        for (int mi = 0; mi < 4; mi++) {
#pragma unroll
            for (int r = 0; r < 4; r++) {
                int row = t0 + wm * 64 + mi * 16 + quad * 4 + r;
                float y = acc[mi][ni][r] * s + bb;
                if (relu) y = fmaxf(y, 0.f);
                Y[((size_t)b * T + row) * ystride + ycol + col] = __float2bfloat16(y);
            }
        }
    }
}

// ---------------- tiny-Cout conv heads ----------------
// one wave per (b,t) row; w: [Cout][Cin][taps] fp32
// mode 0: v = acc + bias ; mode 1: v = exp((acc+bias)*scale)
__global__ __launch_bounds__(256) void small_conv(
    const bf16* __restrict__ X, int T, int xstride, int xcol,
    int Cin, int taps,
    const float* __restrict__ w, const float* __restrict__ bias,
    int Cout, int mode, const float* __restrict__ scale_ptr,
    float* __restrict__ out)
{
    int lane = threadIdx.x & 63, wv = threadIdx.x >> 6;
    int row = blockIdx.x * 4 + wv;
    int b = row / T, t = row - b * T;
    int cpl = Cin >> 6;  // channels per lane (8 or 4)
    const bf16* xb = X + (size_t)b * T * xstride + xcol + lane * cpl;
    int klo = (taps == 3) ? -1 : 0;
    int khi = (taps == 3) ? 1 : 0;
    for (int co = 0; co < Cout; co++) {
        float acc = 0.f;
        for (int k = klo; k <= khi; k++) {
            int tt = t + k;
            if (tt < 0 || tt >= T) continue;
            const bf16* xr = xb + (size_t)tt * xstride;
            const float* wr = w + ((size_t)co * Cin + lane * cpl) * taps + (k - klo);
            for (int j = 0; j < cpl; j++)
                acc += __bfloat162float(xr[j]) * wr[j * taps];
        }
        for (int off = 32; off; off >>= 1) acc += __shfl_down(acc, off);
        if (lane == 0) {
            float v = acc + bias[co];
            if (mode == 1) v = expf(v * scale_ptr[0]);
            out[((size_t)b * Cout + co) * T + t] = v;
        }
    }
}

// ---------------- launch ----------------
extern "C" void kernel_launch(void* const* d_in, const int* in_sizes, int n_in,
                              void* d_out, int out_size, void* d_ws, size_t ws_size,
                              hipStream_t stream) {
    const float* xin[3] = {(const float*)d_in[0], (const float*)d_in[1], (const float*)d_in[2]};
    const float* cls_w  = (const float*)d_in[3];
    const float* cls_b  = (const float*)d_in[4];
    const float* cls_g  = (const float*)d_in[5];
    const float* cls_be = (const float*)d_in[6];
    const float* cls_m  = (const float*)d_in[7];
    const float* cls_v  = (const float*)d_in[8];
    const float* box_w  = (const float*)d_in[9];
    const float* box_b  = (const float*)d_in[10];
    const float* box_g  = (const float*)d_in[11];
    const float* box_be = (const float*)d_in[12];
    const float* box_m  = (const float*)d_in[13];
    const float* box_v  = (const float*)d_in[14];
    const float* logits_w = (const float*)d_in[15];
    const float* logits_b = (const float*)d_in[16];
    const float* pred_w   = (const float*)d_in[17];
    const float* pred_b   = (const float*)d_in[18];
    const float* scales   = (const float*)d_in[19];
    const float* mix_w  = (const float*)d_in[20];
    const float* mix_b  = (const float*)d_in[21];
    const float* mix_g  = (const float*)d_in[22];
    const float* mix_be = (const float*)d_in[23];
    const float* mix_m  = (const float*)d_in[24];
    const float* mix_v  = (const float*)d_in[25];
    const float* iou_w1 = (const float*)d_in[26];
    const float* iou_b1 = (const float*)d_in[27];
    const float* iou_g  = (const float*)d_in[28];
    const float* iou_be = (const float*)d_in[29];
    const float* iou_m  = (const float*)d_in[30];
    const float* iou_v  = (const float*)d_in[31];
    const float* iou_w2 = (const float*)d_in[32];
    const float* iou_b2 = (const float*)d_in[33];

    float* out = (float*)d_out;
    char* ws = (char*)d_ws;
    bf16* XB   = (bf16*)(ws + OFF_XB);
    bf16* TMP  = (bf16*)(ws + OFF_TMP);
    bf16* CAT  = (bf16*)(ws + OFF_CAT);
    bf16* H    = (bf16*)(ws + OFF_H);
    bf16* WCLS = (bf16*)(ws + OFF_WCLS);
    bf16* WBOX = (bf16*)(ws + OFF_WBOX);
    bf16* WMIX = (bf16*)(ws + OFF_WMIX);
    bf16* WIOU = (bf16*)(ws + OFF_WIOU);
    float* AFF = (float*)(ws + OFF_AFF);
    // AFF layout (floats): cls0 @0, cls1 @1024, box0 @2048, box1 @3072, mix @4096, iou @5120

    // ---- prep ----
    {
        int n = 512 * 512 * 3;
        wtrans<<<(n + 255) / 256, 256, 0, stream>>>(cls_w,     WCLS,     512, 512, 3);
        wtrans<<<(n + 255) / 256, 256, 0, stream>>>(cls_w + n, WCLS + n, 512, 512, 3);
        wtrans<<<(n + 255) / 256, 256, 0, stream>>>(box_w,     WBOX,     512, 512, 3);
        wtrans<<<(n + 255) / 256, 256, 0, stream>>>(box_w + n, WBOX + n, 512, 512, 3);
        int n2 = 512 * 1024;
        wtrans<<<(n2 + 255) / 256, 256, 0, stream>>>(mix_w, WMIX, 512, 1024, 1);
        int n3 = 256 * 512 * 3;
        wtrans<<<(n3 + 255) / 256, 256, 0, stream>>>(iou_w1, WIOU, 256, 512, 3);

        mkaff<<<2, 256, 0, stream>>>(cls_g,       cls_be,       cls_m,       cls_v,       cls_b,       AFF + 0,    512);
        mkaff<<<2, 256, 0, stream>>>(cls_g + 512, cls_be + 512, cls_m + 512, cls_v + 512, cls_b + 512, AFF + 1024, 512);
        mkaff<<<2, 256, 0, stream>>>(box_g,       box_be,       box_m,       box_v,       box_b,       AFF + 2048, 512);
        mkaff<<<2, 256, 0, stream>>>(box_g + 512, box_be + 512, box_m + 512, box_v + 512, box_b + 512, AFF + 3072, 512);
        mkaff<<<2, 256, 0, stream>>>(mix_g, mix_be, mix_m, mix_v, mix_b,  AFF + 4096, 512);
        mkaff<<<1, 256, 0, stream>>>(iou_g, iou_be, iou_m, iou_v, iou_b1, AFF + 5120, 256);

        locs_k<<<7, 256, 0, stream>>>(out + 229376);
    }

    const int Ts[3] = {1024, 512, 256};
    const int LOGITS_OFF[3] = {0, 32768, 49152};
    const int BBOX_OFF[3]   = {57344, 122880, 155648};
    const int IOU_OFF[3]    = {172032, 204800, 221184};
    const int WLAYER = 512 * 512 * 3;  // bf16 elements per tower layer

    for (int lvl = 0; lvl < 3; lvl++) {
        int T = Ts[lvl];
        // x -> [B][T][512] bf16
        transpose_cvt<<<dim3(T / 32, 16, 32), dim3(32, 8), 0, stream>>>(xin[lvl], XB, T);

        // cls tower
        conv_mfma<<<dim3(4, T / 128, 32), 256, 0, stream>>>(
            XB, T, 512, 512, WCLS, 3, 512, AFF + 0, TMP, 512, 0, 1);
        conv_mfma<<<dim3(4, T / 128, 32), 256, 0, stream>>>(
            TMP, T, 512, 512, WCLS + WLAYER, 3, 512, AFF + 1024, CAT, 1024, 0, 1);
        // box tower
        conv_mfma<<<dim3(4, T / 128, 32), 256, 0, stream>>>(
            XB, T, 512, 512, WBOX, 3, 512, AFF + 2048, TMP, 512, 0, 1);
        conv_mfma<<<dim3(4, T / 128, 32), 256, 0, stream>>>(
            TMP, T, 512, 512, WBOX + WLAYER, 3, 512, AFF + 3072, CAT, 1024, 512, 1);

        // logits / bbox heads
        small_conv<<<32 * T / 4, 256, 0, stream>>>(
            CAT, T, 1024, 0, 512, 3, logits_w, logits_b, 1, 0, scales, out + LOGITS_OFF[lvl]);
        small_conv<<<32 * T / 4, 256, 0, stream>>>(
            CAT, T, 1024, 512, 512, 3, pred_w, pred_b, 2, 1, scales + lvl, out + BBOX_OFF[lvl]);

        // mix (k=1, 1024->512) -> XB
        conv_mfma<<<dim3(4, T / 128, 32), 256, 0, stream>>>(
            CAT, T, 1024, 1024, WMIX, 1, 512, AFF + 4096, XB, 512, 0, 1);
        // iou tower (512->256, k=3) -> H
        conv_mfma<<<dim3(2, T / 128, 32), 256, 0, stream>>>(
            XB, T, 512, 512, WIOU, 3, 256, AFF + 5120, H, 256, 0, 1);
        // iou head (256->1, k=1)
        small_conv<<<32 * T / 4, 256, 0, stream>>>(
            H, T, 256, 0, 256, 1, iou_w2, iou_b2, 1, 0, scales, out + IOU_OFF[lvl]);
    }
}

// Round 2
// 1593.437 us; speedup vs baseline: 1.3676x; 1.3676x over previous
//
#include <hip/hip_runtime.h>
#include <hip/hip_bf16.h>

typedef __hip_bfloat16 bf16;
typedef __attribute__((ext_vector_type(8))) short short8;
typedef __attribute__((ext_vector_type(4))) short short4v;
typedef __attribute__((ext_vector_type(4))) float float4v;

// ---------------- workspace layout (bytes) ----------------
#define SZ_XB   (32ull*1024*512*2)      // [B][1024][512] bf16
#define SZ_CAT  (32ull*1024*1024*2)     // [B][1024][1024] bf16
#define SZ_H    (32ull*1024*256*2)      // [B][1024][256] bf16
#define SZ_WTOW (2ull*3*512*512*2)      // per tower: 2 layers x [3][512][512] bf16
#define SZ_WMIX (512ull*1024*2)
#define SZ_WIOU (3ull*256*512*2)

#define OFF_XB   0ull
#define OFF_TMP  (OFF_XB + SZ_XB)
#define OFF_CAT  (OFF_TMP + SZ_XB)
#define OFF_H    (OFF_CAT + SZ_CAT)
#define OFF_WCLS (OFF_H + SZ_H)
#define OFF_WBOX (OFF_WCLS + SZ_WTOW)
#define OFF_WMIX (OFF_WBOX + SZ_WTOW)
#define OFF_WIOU (OFF_WMIX + SZ_WMIX)
#define OFF_AFF  (OFF_WIOU + SZ_WIOU)

// ---------------- prep kernels ----------------
// [Co][Ci][K] fp32 -> [K][Co][Ci] bf16
__global__ void wtrans(const float* __restrict__ w, bf16* __restrict__ o,
                       int Co, int Ci, int K) {
    long long idx = (long long)blockIdx.x * 256 + threadIdx.x;
    long long n = (long long)Co * Ci * K;
    if (idx >= n) return;
    int ci = (int)(idx % Ci);
    long long r = idx / Ci;
    int co = (int)(r % Co);
    int k  = (int)(r / Co);
    o[idx] = __float2bfloat16(w[((long long)co * Ci + ci) * K + k]);
}

// BN fold: scale = g*rsqrt(v+eps); bias = cb*scale + beta - m*scale
__global__ void mkaff(const float* __restrict__ g, const float* __restrict__ beta,
                      const float* __restrict__ m, const float* __restrict__ v,
                      const float* __restrict__ cb, float* __restrict__ out, int C) {
    int i = blockIdx.x * 256 + threadIdx.x;
    if (i >= C) return;
    float s = g[i] * rsqrtf(v[i] + 1e-5f);
    out[i] = s;
    out[C + i] = cb[i] * s + beta[i] - m[i] * s;
}

// x [B][512][T] fp32 -> xb [B][T][512] bf16
__global__ void transpose_cvt(const float* __restrict__ x, bf16* __restrict__ xb, int T) {
    __shared__ float tile[32][33];
    int t0 = blockIdx.x * 32, c0 = blockIdx.y * 32, b = blockIdx.z;
    const float* xp = x + ((size_t)b * 512 + c0) * T + t0;
    for (int i = 0; i < 4; i++) {
        int c = threadIdx.y + i * 8;
        tile[c][threadIdx.x] = xp[(size_t)c * T + threadIdx.x];
    }
    __syncthreads();
    bf16* yp = xb + ((size_t)b * T + t0) * 512 + c0;
    for (int i = 0; i < 4; i++) {
        int t = threadIdx.y + i * 8;
        yp[(size_t)t * 512 + threadIdx.x] = __float2bfloat16(tile[threadIdx.x][t]);
    }
}

// locations
__global__ void locs_k(float* __restrict__ out) {
    int i = blockIdx.x * 256 + threadIdx.x;
    if (i < 1024)      out[i] = (float)i + 0.5f;
    else if (i < 1536) out[i] = (float)(i - 1024) * 2.0f + 1.0f;
    else if (i < 1792) out[i] = (float)(i - 1536) * 4.0f + 2.0f;
}

// ---------------- main MFMA conv (k=3 pad=1 or k=1 pad=0) + BN + ReLU ----------------
__global__ __launch_bounds__(256) void conv_mfma(
    const bf16* __restrict__ X, int T, int Cin, int xstride,
    const bf16* __restrict__ Wt, int taps, int CoutTot,
    const float* __restrict__ aff,
    bf16* __restrict__ Y, int ystride, int ycol, int relu)
{
    __shared__ short Alds[130 * 40];      // 130 rows x 32 ci, stride 40 (80B)
    __shared__ short Wlds[3 * 128 * 40];  // [tap][128 co][32 ci]

    int co0 = blockIdx.x * 128, t0 = blockIdx.y * 128, b = blockIdx.z;
    int tid = threadIdx.x;
    int lane = tid & 63, wv = tid >> 6;
    int wm = wv >> 1, wn = wv & 1;
    int quad = lane >> 4, l15 = lane & 15;

    float4v acc[4][4] = {};

    int kIters = Cin >> 5;  // 32 ci per iteration
    int arows = (taps == 3) ? 130 : 128;
    int halo = (taps == 3) ? 1 : 0;

    for (int kk = 0; kk < kIters; kk++) {
        int ci0 = kk << 5;
        if (kk) __syncthreads();
        for (int idx = tid; idx < arows * 4; idx += 256) {
            int r = idx >> 2, part = idx & 3;
            int tg = t0 + r - halo;
            short8 v = {0, 0, 0, 0, 0, 0, 0, 0};
            if (tg >= 0 && tg < T)
                v = *(const short8*)(X + ((size_t)b * T + tg) * xstride + ci0 + part * 8);
            *(short8*)&Alds[r * 40 + part * 8] = v;
        }
        for (int idx = tid; idx < taps * 512; idx += 256) {
            int tap = idx >> 9, rem = idx & 511;
            int row = rem >> 2, part = rem & 3;
            short8 v = *(const short8*)(Wt + ((size_t)tap * CoutTot + co0 + row) * Cin + ci0 + part * 8);
            *(short8*)&Wlds[tap * 5120 + row * 40 + part * 8] = v;
        }
        __syncthreads();

        for (int tap = 0; tap < taps; tap++) {
            int rowoff = (taps == 3) ? tap : 0;
            short8 af[4], bfr[4];
#pragma unroll
            for (int mi = 0; mi < 4; mi++)
                af[mi] = *(short8*)&Alds[(wm * 64 + mi * 16 + l15 + rowoff) * 40 + quad * 8];
#pragma unroll
            for (int ni = 0; ni < 4; ni++)
                bfr[ni] = *(short8*)&Wlds[tap * 5120 + (wn * 64 + ni * 16 + l15) * 40 + quad * 8];
#pragma unroll
            for (int mi = 0; mi < 4; mi++)
#pragma unroll
                for (int ni = 0; ni < 4; ni++)
                    acc[mi][ni] = __builtin_amdgcn_mfma_f32_16x16x32_bf16(
                        af[mi], bfr[ni], acc[mi][ni], 0, 0, 0);
        }
    }

#pragma unroll
    for (int ni = 0; ni < 4; ni++) {
        int col = co0 + wn * 64 + ni * 16 + l15;
        float s = 1.f, bb = 0.f;
        if (aff) { s = aff[col]; bb = aff[CoutTot + col]; }
#pragma unroll
        for (int mi = 0; mi < 4; mi++) {
#pragma unroll
            for (int r = 0; r < 4; r++) {
                int row = t0 + wm * 64 + mi * 16 + quad * 4 + r;
                float y = acc[mi][ni][r] * s + bb;
                if (relu) y = fmaxf(y, 0.f);
                Y[((size_t)b * T + row) * ystride + ycol + col] = __float2bfloat16(y);
            }
        }
    }
}

// ---------------- tiny-Cout conv heads (rewritten: vector loads, reg weights, sliding window) ----------------
// one wave handles RW consecutive t-rows of one batch; lane owns CPL channels.
// w: [COUT][Cin][TAPS] fp32. out: [B][COUT][T] fp32.
template<int CPL, int TAPS, int COUT, int MODE>
__global__ __launch_bounds__(256) void head_conv(
    const bf16* __restrict__ X, int T, int xstride, int xcol,
    const float* __restrict__ w, const float* __restrict__ bias,
    const float* __restrict__ scale_ptr, float* __restrict__ out)
{
    constexpr int RW = 16;
    constexpr int Cin = CPL * 64;
    int lane = threadIdx.x & 63, wv = threadIdx.x >> 6;
    int r0 = (blockIdx.x * 4 + wv) * RW;
    int b = r0 / T, t0 = r0 - b * T;
    const bf16* base = X + (size_t)b * T * xstride + xcol + lane * CPL;

    float wr[COUT][TAPS][CPL];
#pragma unroll
    for (int co = 0; co < COUT; co++)
#pragma unroll
        for (int k = 0; k < TAPS; k++)
#pragma unroll
            for (int j = 0; j < CPL; j++)
                wr[co][k][j] = w[((size_t)co * Cin + lane * CPL + j) * TAPS + k];
    float bia[COUT];
#pragma unroll
    for (int co = 0; co < COUT; co++) bia[co] = bias[co];
    float sc = MODE ? scale_ptr[0] : 0.f;

    float fprev[CPL], fcur[CPL], fnext[CPL];

    auto loadrow = [&](int t, float* f) {
        if (t < 0 || t >= T) {
#pragma unroll
            for (int j = 0; j < CPL; j++) f[j] = 0.f;
            return;
        }
        const short* p = (const short*)(base + (size_t)t * xstride);
        if constexpr (CPL == 8) {
            short8 v = *(const short8*)p;
#pragma unroll
            for (int j = 0; j < 8; j++)
                f[j] = __uint_as_float(((unsigned)(unsigned short)v[j]) << 16);
        } else {
            short4v v = *(const short4v*)p;
#pragma unroll
            for (int j = 0; j < CPL; j++)
                f[j] = __uint_as_float(((unsigned)(unsigned short)v[j]) << 16);
        }
    };

    if constexpr (TAPS == 3) { loadrow(t0 - 1, fprev); loadrow(t0, fcur); }

    for (int i = 0; i < RW; i++) {
        int t = t0 + i;
        float acc[COUT];
#pragma unroll
        for (int co = 0; co < COUT; co++) acc[co] = 0.f;
        if constexpr (TAPS == 3) {
            loadrow(t + 1, fnext);
#pragma unroll
            for (int co = 0; co < COUT; co++)
#pragma unroll
                for (int j = 0; j < CPL; j++)
                    acc[co] += fprev[j] * wr[co][0][j] + fcur[j] * wr[co][1][j]
                             + fnext[j] * wr[co][2][j];
#pragma unroll
            for (int j = 0; j < CPL; j++) { fprev[j] = fcur[j]; fcur[j] = fnext[j]; }
        } else {
            loadrow(t, fcur);
#pragma unroll
            for (int co = 0; co < COUT; co++)
#pragma unroll
                for (int j = 0; j < CPL; j++)
                    acc[co] += fcur[j] * wr[co][0][j];
        }
#pragma unroll
        for (int co = 0; co < COUT; co++)
#pragma unroll
            for (int off = 32; off; off >>= 1)
                acc[co] += __shfl_down(acc[co], off);
        if (lane == 0) {
#pragma unroll
            for (int co = 0; co < COUT; co++) {
                float v = acc[co] + bia[co];
                if (MODE) v = expf(v * sc);
                out[((size_t)b * COUT + co) * T + t] = v;
            }
        }
    }
}

// ---------------- launch ----------------
extern "C" void kernel_launch(void* const* d_in, const int* in_sizes, int n_in,
                              void* d_out, int out_size, void* d_ws, size_t ws_size,
                              hipStream_t stream) {
    const float* xin[3] = {(const float*)d_in[0], (const float*)d_in[1], (const float*)d_in[2]};
    const float* cls_w  = (const float*)d_in[3];
    const float* cls_b  = (const float*)d_in[4];
    const float* cls_g  = (const float*)d_in[5];
    const float* cls_be = (const float*)d_in[6];
    const float* cls_m  = (const float*)d_in[7];
    const float* cls_v  = (const float*)d_in[8];
    const float* box_w  = (const float*)d_in[9];
    const float* box_b  = (const float*)d_in[10];
    const float* box_g  = (const float*)d_in[11];
    const float* box_be = (const float*)d_in[12];
    const float* box_m  = (const float*)d_in[13];
    const float* box_v  = (const float*)d_in[14];
    const float* logits_w = (const float*)d_in[15];
    const float* logits_b = (const float*)d_in[16];
    const float* pred_w   = (const float*)d_in[17];
    const float* pred_b   = (const float*)d_in[18];
    const float* scales   = (const float*)d_in[19];
    const float* mix_w  = (const float*)d_in[20];
    const float* mix_b  = (const float*)d_in[21];
    const float* mix_g  = (const float*)d_in[22];
    const float* mix_be = (const float*)d_in[23];
    const float* mix_m  = (const float*)d_in[24];
    const float* mix_v  = (const float*)d_in[25];
    const float* iou_w1 = (const float*)d_in[26];
    const float* iou_b1 = (const float*)d_in[27];
    const float* iou_g  = (const float*)d_in[28];
    const float* iou_be = (const float*)d_in[29];
    const float* iou_m  = (const float*)d_in[30];
    const float* iou_v  = (const float*)d_in[31];
    const float* iou_w2 = (const float*)d_in[32];
    const float* iou_b2 = (const float*)d_in[33];

    float* out = (float*)d_out;
    char* ws = (char*)d_ws;
    bf16* XB   = (bf16*)(ws + OFF_XB);
    bf16* TMP  = (bf16*)(ws + OFF_TMP);
    bf16* CAT  = (bf16*)(ws + OFF_CAT);
    bf16* H    = (bf16*)(ws + OFF_H);
    bf16* WCLS = (bf16*)(ws + OFF_WCLS);
    bf16* WBOX = (bf16*)(ws + OFF_WBOX);
    bf16* WMIX = (bf16*)(ws + OFF_WMIX);
    bf16* WIOU = (bf16*)(ws + OFF_WIOU);
    float* AFF = (float*)(ws + OFF_AFF);

    // ---- prep ----
    {
        int n = 512 * 512 * 3;
        wtrans<<<(n + 255) / 256, 256, 0, stream>>>(cls_w,     WCLS,     512, 512, 3);
        wtrans<<<(n + 255) / 256, 256, 0, stream>>>(cls_w + n, WCLS + n, 512, 512, 3);
        wtrans<<<(n + 255) / 256, 256, 0, stream>>>(box_w,     WBOX,     512, 512, 3);
        wtrans<<<(n + 255) / 256, 256, 0, stream>>>(box_w + n, WBOX + n, 512, 512, 3);
        int n2 = 512 * 1024;
        wtrans<<<(n2 + 255) / 256, 256, 0, stream>>>(mix_w, WMIX, 512, 1024, 1);
        int n3 = 256 * 512 * 3;
        wtrans<<<(n3 + 255) / 256, 256, 0, stream>>>(iou_w1, WIOU, 256, 512, 3);

        mkaff<<<2, 256, 0, stream>>>(cls_g,       cls_be,       cls_m,       cls_v,       cls_b,       AFF + 0,    512);
        mkaff<<<2, 256, 0, stream>>>(cls_g + 512, cls_be + 512, cls_m + 512, cls_v + 512, cls_b + 512, AFF + 1024, 512);
        mkaff<<<2, 256, 0, stream>>>(box_g,       box_be,       box_m,       box_v,       box_b,       AFF + 2048, 512);
        mkaff<<<2, 256, 0, stream>>>(box_g + 512, box_be + 512, box_m + 512, box_v + 512, box_b + 512, AFF + 3072, 512);
        mkaff<<<2, 256, 0, stream>>>(mix_g, mix_be, mix_m, mix_v, mix_b,  AFF + 4096, 512);
        mkaff<<<1, 256, 0, stream>>>(iou_g, iou_be, iou_m, iou_v, iou_b1, AFF + 5120, 256);

        locs_k<<<7, 256, 0, stream>>>(out + 229376);
    }

    const int Ts[3] = {1024, 512, 256};
    const int LOGITS_OFF[3] = {0, 32768, 49152};
    const int BBOX_OFF[3]   = {57344, 122880, 155648};
    const int IOU_OFF[3]    = {172032, 204800, 221184};
    const int WLAYER = 512 * 512 * 3;

    for (int lvl = 0; lvl < 3; lvl++) {
        int T = Ts[lvl];
        transpose_cvt<<<dim3(T / 32, 16, 32), dim3(32, 8), 0, stream>>>(xin[lvl], XB, T);

        // cls tower
        conv_mfma<<<dim3(4, T / 128, 32), 256, 0, stream>>>(
            XB, T, 512, 512, WCLS, 3, 512, AFF + 0, TMP, 512, 0, 1);
        conv_mfma<<<dim3(4, T / 128, 32), 256, 0, stream>>>(
            TMP, T, 512, 512, WCLS + WLAYER, 3, 512, AFF + 1024, CAT, 1024, 0, 1);
        // box tower
        conv_mfma<<<dim3(4, T / 128, 32), 256, 0, stream>>>(
            XB, T, 512, 512, WBOX, 3, 512, AFF + 2048, TMP, 512, 0, 1);
        conv_mfma<<<dim3(4, T / 128, 32), 256, 0, stream>>>(
            TMP, T, 512, 512, WBOX + WLAYER, 3, 512, AFF + 3072, CAT, 1024, 512, 1);

        // logits / bbox heads (vectorized)
        head_conv<8, 3, 1, 0><<<T / 2, 256, 0, stream>>>(
            CAT, T, 1024, 0, logits_w, logits_b, scales, out + LOGITS_OFF[lvl]);
        head_conv<8, 3, 2, 1><<<T / 2, 256, 0, stream>>>(
            CAT, T, 1024, 512, pred_w, pred_b, scales + lvl, out + BBOX_OFF[lvl]);

        // mix (k=1, 1024->512) -> XB
        conv_mfma<<<dim3(4, T / 128, 32), 256, 0, stream>>>(
            CAT, T, 1024, 1024, WMIX, 1, 512, AFF + 4096, XB, 512, 0, 1);
        // iou tower (512->256, k=3) -> H
        conv_mfma<<<dim3(2, T / 128, 32), 256, 0, stream>>>(
            XB, T, 512, 512, WIOU, 3, 256, AFF + 5120, H, 256, 0, 1);
        // iou head (256->1, k=1)
        head_conv<4, 1, 1, 0><<<T / 2, 256, 0, stream>>>(
            H, T, 256, 0, iou_w2, iou_b2, scales, out + IOU_OFF[lvl]);
    }
}

// Round 3
// 1039.969 us; speedup vs baseline: 2.0955x; 1.5322x over previous
//
#include <hip/hip_runtime.h>
#include <hip/hip_bf16.h>

typedef __hip_bfloat16 bf16;
typedef __attribute__((ext_vector_type(8))) short short8;
typedef __attribute__((ext_vector_type(4))) short short4v;
typedef __attribute__((ext_vector_type(4))) float float4v;

// ---------------- workspace layout (bytes) ----------------
#define SZ_XB   (32ull*1024*512*2)      // [B][1024][512] bf16
#define SZ_CAT  (32ull*1024*1024*2)     // [B][1024][1024] bf16
#define SZ_H    (32ull*1024*256*2)      // [B][1024][256] bf16
#define SZ_WTOW (2ull*3*512*512*2)      // per tower: 2 layers x [3][512][512] bf16
#define SZ_WMIX (512ull*1024*2)
#define SZ_WIOU (3ull*256*512*2)

#define OFF_XB   0ull
#define OFF_TMP  (OFF_XB + SZ_XB)
#define OFF_CAT  (OFF_TMP + SZ_XB)
#define OFF_H    (OFF_CAT + SZ_CAT)
#define OFF_WCLS (OFF_H + SZ_H)
#define OFF_WBOX (OFF_WCLS + SZ_WTOW)
#define OFF_WMIX (OFF_WBOX + SZ_WTOW)
#define OFF_WIOU (OFF_WMIX + SZ_WMIX)
#define OFF_AFF  (OFF_WIOU + SZ_WIOU)

// async global->LDS, 16B per lane; lds base must be wave-uniform
__device__ __forceinline__ void gl2lds16(const bf16* g, short* l) {
    __builtin_amdgcn_global_load_lds(
        (const __attribute__((address_space(1))) unsigned int*)g,
        (__attribute__((address_space(3))) unsigned int*)l, 16, 0, 0);
}

// ---------------- prep kernels ----------------
// [Co][Ci][K] fp32 -> [K][Co][Ci] bf16
__global__ void wtrans(const float* __restrict__ w, bf16* __restrict__ o,
                       int Co, int Ci, int K) {
    long long idx = (long long)blockIdx.x * 256 + threadIdx.x;
    long long n = (long long)Co * Ci * K;
    if (idx >= n) return;
    int ci = (int)(idx % Ci);
    long long r = idx / Ci;
    int co = (int)(r % Co);
    int k  = (int)(r / Co);
    o[idx] = __float2bfloat16(w[((long long)co * Ci + ci) * K + k]);
}

// BN fold: scale = g*rsqrt(v+eps); bias = cb*scale + beta - m*scale
__global__ void mkaff(const float* __restrict__ g, const float* __restrict__ beta,
                      const float* __restrict__ m, const float* __restrict__ v,
                      const float* __restrict__ cb, float* __restrict__ out, int C) {
    int i = blockIdx.x * 256 + threadIdx.x;
    if (i >= C) return;
    float s = g[i] * rsqrtf(v[i] + 1e-5f);
    out[i] = s;
    out[C + i] = cb[i] * s + beta[i] - m[i] * s;
}

// x [B][512][T] fp32 -> xb [B][T][512] bf16
__global__ void transpose_cvt(const float* __restrict__ x, bf16* __restrict__ xb, int T) {
    __shared__ float tile[32][33];
    int t0 = blockIdx.x * 32, c0 = blockIdx.y * 32, b = blockIdx.z;
    const float* xp = x + ((size_t)b * 512 + c0) * T + t0;
    for (int i = 0; i < 4; i++) {
        int c = threadIdx.y + i * 8;
        tile[c][threadIdx.x] = xp[(size_t)c * T + threadIdx.x];
    }
    __syncthreads();
    bf16* yp = xb + ((size_t)b * T + t0) * 512 + c0;
    for (int i = 0; i < 4; i++) {
        int t = threadIdx.y + i * 8;
        yp[(size_t)t * 512 + threadIdx.x] = __float2bfloat16(tile[threadIdx.x][t]);
    }
}

// locations
__global__ void locs_k(float* __restrict__ out) {
    int i = blockIdx.x * 256 + threadIdx.x;
    if (i < 1024)      out[i] = (float)i + 0.5f;
    else if (i < 1536) out[i] = (float)(i - 1024) * 2.0f + 1.0f;
    else if (i < 1792) out[i] = (float)(i - 1536) * 4.0f + 2.0f;
}

// ---------------- main MFMA conv (k=3 pad=1 or k=1 pad=0) + BN + ReLU ----------------
// X: [B][T][xstride] bf16 ; Wt: [taps][CoutTot][Cin] bf16 ; Y: [B][T][ystride] bf16 at col ycol
// LDS unpadded (stride 32 shorts = 64B) to satisfy global_load_lds lane-order layout.
__global__ __launch_bounds__(256, 4) void conv_mfma(
    const bf16* __restrict__ X, int T, int Cin, int xstride,
    const bf16* __restrict__ Wt, int taps, int CoutTot,
    const float* __restrict__ aff,
    bf16* __restrict__ Y, int ystride, int ycol, int relu)
{
    __shared__ short Alds[130 * 32];      // rows x 32 ci, 64B row stride
    __shared__ short Wlds[3 * 128 * 32];  // [tap][128 co][32 ci]

    int co0 = blockIdx.x * 128, t0 = blockIdx.y * 128, b = blockIdx.z;
    int tid = threadIdx.x;
    int lane = tid & 63, wv = tid >> 6;
    int wm = wv >> 1, wn = wv & 1;
    int quad = lane >> 4, l15 = lane & 15;
    int lr = lane >> 2, lp = lane & 3;    // row-in-16-chunk, 16B part

    float4v acc[4][4] = {};

    int kIters = Cin >> 5;                // 32 ci per iteration
    int row0 = (taps == 3) ? 1 : 0;       // halo offset in Alds

    for (int kk = 0; kk < kIters; kk++) {
        int ci0 = kk << 5;
        if (kk) __syncthreads();

        // async stage A interior rows (always in-bounds): 8 wave-instructions
        for (int inst = wv; inst < 8; inst += 4) {
            int row = inst * 16 + lr;                       // 0..127
            const bf16* g = X + ((size_t)b * T + t0 + row) * xstride + ci0 + lp * 8;
            gl2lds16(g, &Alds[(row0 + inst * 16) * 32]);
        }
        // async stage W: taps*8 wave-instructions
        for (int inst = wv; inst < taps * 8; inst += 4) {
            int tap = inst >> 3, i2 = inst & 7;
            int row = i2 * 16 + lr;                         // 0..127
            const bf16* g = Wt + ((size_t)tap * CoutTot + co0 + row) * Cin + ci0 + lp * 8;
            gl2lds16(g, &Wlds[tap * 4096 + i2 * 512]);
        }
        // halo rows (bounds-checked, zero-fill), rows 0 and 129
        if (taps == 3 && tid < 8) {
            int top = tid >> 2;
            int h = top ? 129 : 0;
            int tg = top ? t0 + 128 : t0 - 1;
            int part = tid & 3;
            short8 v = {0, 0, 0, 0, 0, 0, 0, 0};
            if (tg >= 0 && tg < T)
                v = *(const short8*)(X + ((size_t)b * T + tg) * xstride + ci0 + part * 8);
            *(short8*)&Alds[h * 32 + part * 8] = v;
        }
        __syncthreads();

        for (int tap = 0; tap < taps; tap++) {
            short8 af[4], bfr[4];
#pragma unroll
            for (int mi = 0; mi < 4; mi++)
                af[mi] = *(short8*)&Alds[(wm * 64 + mi * 16 + l15 + tap) * 32 + quad * 8];
#pragma unroll
            for (int ni = 0; ni < 4; ni++)
                bfr[ni] = *(short8*)&Wlds[tap * 4096 + (wn * 64 + ni * 16 + l15) * 32 + quad * 8];
#pragma unroll
            for (int mi = 0; mi < 4; mi++)
#pragma unroll
                for (int ni = 0; ni < 4; ni++)
                    acc[mi][ni] = __builtin_amdgcn_mfma_f32_16x16x32_bf16(
                        af[mi], bfr[ni], acc[mi][ni], 0, 0, 0);
        }
    }

    // epilogue: affine + relu + bf16 store
#pragma unroll
    for (int ni = 0; ni < 4; ni++) {
        int col = co0 + wn * 64 + ni * 16 + l15;
        float s = aff[col], bb = aff[CoutTot + col];
#pragma unroll
        for (int mi = 0; mi < 4; mi++) {
#pragma unroll
            for (int r = 0; r < 4; r++) {
                int row = t0 + wm * 64 + mi * 16 + quad * 4 + r;
                float y = acc[mi][ni][r] * s + bb;
                if (relu) y = fmaxf(y, 0.f);
                Y[((size_t)b * T + row) * ystride + ycol + col] = __float2bfloat16(y);
            }
        }
    }
}

// ---------------- tiny-Cout conv heads ----------------
template<int CPL, int TAPS, int COUT, int MODE>
__global__ __launch_bounds__(256) void head_conv(
    const bf16* __restrict__ X, int T, int xstride, int xcol,
    const float* __restrict__ w, const float* __restrict__ bias,
    const float* __restrict__ scale_ptr, float* __restrict__ out)
{
    constexpr int RW = 16;
    constexpr int Cin = CPL * 64;
    int lane = threadIdx.x & 63, wv = threadIdx.x >> 6;
    int r0 = (blockIdx.x * 4 + wv) * RW;
    int b = r0 / T, t0 = r0 - b * T;
    const bf16* base = X + (size_t)b * T * xstride + xcol + lane * CPL;

    float wr[COUT][TAPS][CPL];
#pragma unroll
    for (int co = 0; co < COUT; co++)
#pragma unroll
        for (int k = 0; k < TAPS; k++)
#pragma unroll
            for (int j = 0; j < CPL; j++)
                wr[co][k][j] = w[((size_t)co * Cin + lane * CPL + j) * TAPS + k];
    float bia[COUT];
#pragma unroll
    for (int co = 0; co < COUT; co++) bia[co] = bias[co];
    float sc = MODE ? scale_ptr[0] : 0.f;

    float fprev[CPL], fcur[CPL], fnext[CPL];

    auto loadrow = [&](int t, float* f) {
        if (t < 0 || t >= T) {
#pragma unroll
            for (int j = 0; j < CPL; j++) f[j] = 0.f;
            return;
        }
        const short* p = (const short*)(base + (size_t)t * xstride);
        if constexpr (CPL == 8) {
            short8 v = *(const short8*)p;
#pragma unroll
            for (int j = 0; j < 8; j++)
                f[j] = __uint_as_float(((unsigned)(unsigned short)v[j]) << 16);
        } else {
            short4v v = *(const short4v*)p;
#pragma unroll
            for (int j = 0; j < CPL; j++)
                f[j] = __uint_as_float(((unsigned)(unsigned short)v[j]) << 16);
        }
    };

    if constexpr (TAPS == 3) { loadrow(t0 - 1, fprev); loadrow(t0, fcur); }

    for (int i = 0; i < RW; i++) {
        int t = t0 + i;
        float acc[COUT];
#pragma unroll
        for (int co = 0; co < COUT; co++) acc[co] = 0.f;
        if constexpr (TAPS == 3) {
            loadrow(t + 1, fnext);
#pragma unroll
            for (int co = 0; co < COUT; co++)
#pragma unroll
                for (int j = 0; j < CPL; j++)
                    acc[co] += fprev[j] * wr[co][0][j] + fcur[j] * wr[co][1][j]
                             + fnext[j] * wr[co][2][j];
#pragma unroll
            for (int j = 0; j < CPL; j++) { fprev[j] = fcur[j]; fcur[j] = fnext[j]; }
        } else {
            loadrow(t, fcur);
#pragma unroll
            for (int co = 0; co < COUT; co++)
#pragma unroll
                for (int j = 0; j < CPL; j++)
                    acc[co] += fcur[j] * wr[co][0][j];
        }
#pragma unroll
        for (int co = 0; co < COUT; co++)
#pragma unroll
            for (int off = 32; off; off >>= 1)
                acc[co] += __shfl_down(acc[co], off);
        if (lane == 0) {
#pragma unroll
            for (int co = 0; co < COUT; co++) {
                float v = acc[co] + bia[co];
                if (MODE) v = expf(v * sc);
                out[((size_t)b * COUT + co) * T + t] = v;
            }
        }
    }
}

// ---------------- launch ----------------
extern "C" void kernel_launch(void* const* d_in, const int* in_sizes, int n_in,
                              void* d_out, int out_size, void* d_ws, size_t ws_size,
                              hipStream_t stream) {
    const float* xin[3] = {(const float*)d_in[0], (const float*)d_in[1], (const float*)d_in[2]};
    const float* cls_w  = (const float*)d_in[3];
    const float* cls_b  = (const float*)d_in[4];
    const float* cls_g  = (const float*)d_in[5];
    const float* cls_be = (const float*)d_in[6];
    const float* cls_m  = (const float*)d_in[7];
    const float* cls_v  = (const float*)d_in[8];
    const float* box_w  = (const float*)d_in[9];
    const float* box_b  = (const float*)d_in[10];
    const float* box_g  = (const float*)d_in[11];
    const float* box_be = (const float*)d_in[12];
    const float* box_m  = (const float*)d_in[13];
    const float* box_v  = (const float*)d_in[14];
    const float* logits_w = (const float*)d_in[15];
    const float* logits_b = (const float*)d_in[16];
    const float* pred_w   = (const float*)d_in[17];
    const float* pred_b   = (const float*)d_in[18];
    const float* scales   = (const float*)d_in[19];
    const float* mix_w  = (const float*)d_in[20];
    const float* mix_b  = (const float*)d_in[21];
    const float* mix_g  = (const float*)d_in[22];
    const float* mix_be = (const float*)d_in[23];
    const float* mix_m  = (const float*)d_in[24];
    const float* mix_v  = (const float*)d_in[25];
    const float* iou_w1 = (const float*)d_in[26];
    const float* iou_b1 = (const float*)d_in[27];
    const float* iou_g  = (const float*)d_in[28];
    const float* iou_be = (const float*)d_in[29];
    const float* iou_m  = (const float*)d_in[30];
    const float* iou_v  = (const float*)d_in[31];
    const float* iou_w2 = (const float*)d_in[32];
    const float* iou_b2 = (const float*)d_in[33];

    float* out = (float*)d_out;
    char* ws = (char*)d_ws;
    bf16* XB   = (bf16*)(ws + OFF_XB);
    bf16* TMP  = (bf16*)(ws + OFF_TMP);
    bf16* CAT  = (bf16*)(ws + OFF_CAT);
    bf16* H    = (bf16*)(ws + OFF_H);
    bf16* WCLS = (bf16*)(ws + OFF_WCLS);
    bf16* WBOX = (bf16*)(ws + OFF_WBOX);
    bf16* WMIX = (bf16*)(ws + OFF_WMIX);
    bf16* WIOU = (bf16*)(ws + OFF_WIOU);
    float* AFF = (float*)(ws + OFF_AFF);

    // ---- prep ----
    {
        int n = 512 * 512 * 3;
        wtrans<<<(n + 255) / 256, 256, 0, stream>>>(cls_w,     WCLS,     512, 512, 3);
        wtrans<<<(n + 255) / 256, 256, 0, stream>>>(cls_w + n, WCLS + n, 512, 512, 3);
        wtrans<<<(n + 255) / 256, 256, 0, stream>>>(box_w,     WBOX,     512, 512, 3);
        wtrans<<<(n + 255) / 256, 256, 0, stream>>>(box_w + n, WBOX + n, 512, 512, 3);
        int n2 = 512 * 1024;
        wtrans<<<(n2 + 255) / 256, 256, 0, stream>>>(mix_w, WMIX, 512, 1024, 1);
        int n3 = 256 * 512 * 3;
        wtrans<<<(n3 + 255) / 256, 256, 0, stream>>>(iou_w1, WIOU, 256, 512, 3);

        mkaff<<<2, 256, 0, stream>>>(cls_g,       cls_be,       cls_m,       cls_v,       cls_b,       AFF + 0,    512);
        mkaff<<<2, 256, 0, stream>>>(cls_g + 512, cls_be + 512, cls_m + 512, cls_v + 512, cls_b + 512, AFF + 1024, 512);
        mkaff<<<2, 256, 0, stream>>>(box_g,       box_be,       box_m,       box_v,       box_b,       AFF + 2048, 512);
        mkaff<<<2, 256, 0, stream>>>(box_g + 512, box_be + 512, box_m + 512, box_v + 512, box_b + 512, AFF + 3072, 512);
        mkaff<<<2, 256, 0, stream>>>(mix_g, mix_be, mix_m, mix_v, mix_b,  AFF + 4096, 512);
        mkaff<<<1, 256, 0, stream>>>(iou_g, iou_be, iou_m, iou_v, iou_b1, AFF + 5120, 256);

        locs_k<<<7, 256, 0, stream>>>(out + 229376);
    }

    const int Ts[3] = {1024, 512, 256};
    const int LOGITS_OFF[3] = {0, 32768, 49152};
    const int BBOX_OFF[3]   = {57344, 122880, 155648};
    const int IOU_OFF[3]    = {172032, 204800, 221184};
    const int WLAYER = 512 * 512 * 3;

    for (int lvl = 0; lvl < 3; lvl++) {
        int T = Ts[lvl];
        transpose_cvt<<<dim3(T / 32, 16, 32), dim3(32, 8), 0, stream>>>(xin[lvl], XB, T);

        // cls tower
        conv_mfma<<<dim3(4, T / 128, 32), 256, 0, stream>>>(
            XB, T, 512, 512, WCLS, 3, 512, AFF + 0, TMP, 512, 0, 1);
        conv_mfma<<<dim3(4, T / 128, 32), 256, 0, stream>>>(
            TMP, T, 512, 512, WCLS + WLAYER, 3, 512, AFF + 1024, CAT, 1024, 0, 1);
        // box tower
        conv_mfma<<<dim3(4, T / 128, 32), 256, 0, stream>>>(
            XB, T, 512, 512, WBOX, 3, 512, AFF + 2048, TMP, 512, 0, 1);
        conv_mfma<<<dim3(4, T / 128, 32), 256, 0, stream>>>(
            TMP, T, 512, 512, WBOX + WLAYER, 3, 512, AFF + 3072, CAT, 1024, 512, 1);

        // logits / bbox heads
        head_conv<8, 3, 1, 0><<<T / 2, 256, 0, stream>>>(
            CAT, T, 1024, 0, logits_w, logits_b, scales, out + LOGITS_OFF[lvl]);
        head_conv<8, 3, 2, 1><<<T / 2, 256, 0, stream>>>(
            CAT, T, 1024, 512, pred_w, pred_b, scales + lvl, out + BBOX_OFF[lvl]);

        // mix (k=1, 1024->512) -> XB
        conv_mfma<<<dim3(4, T / 128, 32), 256, 0, stream>>>(
            CAT, T, 1024, 1024, WMIX, 1, 512, AFF + 4096, XB, 512, 0, 1);
        // iou tower (512->256, k=3) -> H
        conv_mfma<<<dim3(2, T / 128, 32), 256, 0, stream>>>(
            XB, T, 512, 512, WIOU, 3, 256, AFF + 5120, H, 256, 0, 1);
        // iou head (256->1, k=1)
        head_conv<4, 1, 1, 0><<<T / 2, 256, 0, stream>>>(
            H, T, 256, 0, iou_w2, iou_b2, scales, out + IOU_OFF[lvl]);
    }
}

// Round 4
// 945.125 us; speedup vs baseline: 2.3058x; 1.1004x over previous
//
#include <hip/hip_runtime.h>
#include <hip/hip_bf16.h>

typedef __hip_bfloat16 bf16;
typedef __attribute__((ext_vector_type(8))) short short8;
typedef __attribute__((ext_vector_type(4))) short short4v;
typedef __attribute__((ext_vector_type(4))) float float4v;

// ---------------- workspace layout (bytes) ----------------
// 4 ping-pong activation buffers [32][1024][512] bf16 (33.55 MB each)
#define SZ_BUF  (32ull*1024*512*2)
#define OFF_B0  0ull
#define OFF_B1  (OFF_B0 + SZ_BUF)
#define OFF_B2  (OFF_B1 + SZ_BUF)
#define OFF_B3  (OFF_B2 + SZ_BUF)
#define OFF_W1  (OFF_B3 + SZ_BUF)            // [3][1024][512] bf16 (cls1 || box1)
#define SZ_W12  (3ull*1024*512*2)
#define OFF_W2  (OFF_W1 + SZ_W12)            // [3][1024][512] bf16 (cls2 || box2)
#define OFF_WMIX (OFF_W2 + SZ_W12)           // [1][512][1024]
#define SZ_WMIX (512ull*1024*2)
#define OFF_WIOU (OFF_WMIX + SZ_WMIX)        // [3][256][512]
#define SZ_WIOU (3ull*256*512*2)
#define OFF_AFF  (OFF_WIOU + SZ_WIOU)        // floats: AFF1[2048] AFF2[2048] AFFM[1024] AFFI[512]

// async global->LDS, 16B per lane; lds base must be wave-uniform
__device__ __forceinline__ void gl2lds16(const bf16* g, short* l) {
    __builtin_amdgcn_global_load_lds(
        (const __attribute__((address_space(1))) unsigned int*)g,
        (__attribute__((address_space(3))) unsigned int*)l, 16, 0, 0);
}

// ---------------- prep kernels ----------------
// [Co][Ci][K] fp32 -> dest[k][coOff+co][ci] bf16 (dest co-dim = CoTot)
__global__ void wtrans(const float* __restrict__ w, bf16* __restrict__ o,
                       int Co, int Ci, int K, int CoTot, int coOff) {
    long long idx = (long long)blockIdx.x * 256 + threadIdx.x;
    long long n = (long long)Co * Ci * K;
    if (idx >= n) return;
    int ci = (int)(idx % Ci);
    long long r = idx / Ci;
    int co = (int)(r % Co);
    int k  = (int)(r / Co);
    o[((size_t)k * CoTot + coOff + co) * Ci + ci] =
        __float2bfloat16(w[((long long)co * Ci + ci) * K + k]);
}

// BN fold: out[i]=scale, out[S+i]=bias
__global__ void mkaff(const float* __restrict__ g, const float* __restrict__ beta,
                      const float* __restrict__ m, const float* __restrict__ v,
                      const float* __restrict__ cb, float* __restrict__ out, int C, int S) {
    int i = blockIdx.x * 256 + threadIdx.x;
    if (i >= C) return;
    float s = g[i] * rsqrtf(v[i] + 1e-5f);
    out[i] = s;
    out[S + i] = cb[i] * s + beta[i] - m[i] * s;
}

// x [B][512][T] fp32 -> xb [B][T][512] bf16
__global__ void transpose_cvt(const float* __restrict__ x, bf16* __restrict__ xb, int T) {
    __shared__ float tile[32][33];
    int t0 = blockIdx.x * 32, c0 = blockIdx.y * 32, b = blockIdx.z;
    const float* xp = x + ((size_t)b * 512 + c0) * T + t0;
    for (int i = 0; i < 4; i++) {
        int c = threadIdx.y + i * 8;
        tile[c][threadIdx.x] = xp[(size_t)c * T + threadIdx.x];
    }
    __syncthreads();
    bf16* yp = xb + ((size_t)b * T + t0) * 512 + c0;
    for (int i = 0; i < 4; i++) {
        int t = threadIdx.y + i * 8;
        yp[(size_t)t * 512 + threadIdx.x] = __float2bfloat16(tile[threadIdx.x][t]);
    }
}

// locations
__global__ void locs_k(float* __restrict__ out) {
    int i = blockIdx.x * 256 + threadIdx.x;
    if (i < 1024)      out[i] = (float)i + 0.5f;
    else if (i < 1536) out[i] = (float)(i - 1024) * 2.0f + 1.0f;
    else if (i < 1792) out[i] = (float)(i - 1536) * 4.0f + 2.0f;
}

// ---------------- main MFMA conv (k=3 pad=1 or k=1 pad=0) + BN + ReLU ----------------
// X select: block (bx<xbsel ? Xa : Xb); ci>=xsplit -> Xc at (ci-xsplit). All X stride 512.
// Y select: bx<ybsel -> Ya at col co0, else Yb at col co0-512. Y stride = ystride.
// LDS bank-conflict swizzle: slot(row,part) = (part + (row>>1)) & 3, applied by permuting
// which global 16B part each DMA lane fetches (LDS dest of global_load_lds is fixed).
__global__ __launch_bounds__(256, 4) void conv_mfma(
    const bf16* __restrict__ Xa, const bf16* __restrict__ Xb, int xbsel,
    const bf16* __restrict__ Xc, int xsplit,
    int T, int Cin,
    const bf16* __restrict__ Wt, int taps, int CoutTot,
    const float* __restrict__ aff,
    bf16* __restrict__ Ya, bf16* __restrict__ Yb, int ybsel, int ystride,
    int relu)
{
    __shared__ short Alds[130 * 32];      // rows x 32 ci, 64B row stride, swizzled slots
    __shared__ short Wlds[3 * 128 * 32];  // [tap][128 co][32 ci], swizzled slots

    int co0 = blockIdx.x * 128, t0 = blockIdx.y * 128, b = blockIdx.z;
    int tid = threadIdx.x;
    int lane = tid & 63, wv = tid >> 6;
    int wm = wv >> 1, wn = wv & 1;
    int quad = lane >> 4, l15 = lane & 15;
    int lr = lane >> 2, lp = lane & 3;

    const bf16* X0 = (blockIdx.x < xbsel) ? Xa : Xb;

    float4v acc[4][4] = {};

    int kIters = Cin >> 5;
    int row0 = (taps == 3) ? 1 : 0;

    int pg = (lp - (lr >> 1)) & 3;                 // DMA: global part this lane fetches
    int wslot = ((quad + (l15 >> 1)) & 3) * 8;     // W-frag slot (constant per lane)

    for (int kk = 0; kk < kIters; kk++) {
        int ci0 = kk << 5;
        const bf16* Xk; int cl;
        if (ci0 < xsplit) { Xk = X0; cl = ci0; } else { Xk = Xc; cl = ci0 - xsplit; }
        if (kk) __syncthreads();

        // async stage A interior rows (always in-bounds)
        for (int inst = wv; inst < 8; inst += 4) {
            int row = inst * 16 + lr;
            const bf16* g = Xk + ((size_t)b * T + t0 + row) * 512 + cl + pg * 8;
            gl2lds16(g, &Alds[(row0 + inst * 16) * 32]);
        }
        // async stage W
        for (int inst = wv; inst < taps * 8; inst += 4) {
            int tap = inst >> 3, i2 = inst & 7;
            int row = i2 * 16 + lr;
            const bf16* g = Wt + ((size_t)tap * CoutTot + co0 + row) * Cin + ci0 + pg * 8;
            gl2lds16(g, &Wlds[tap * 4096 + i2 * 512]);
        }
        // halo rows (bounds-checked, zero-fill): LDS rows 0 (r=-1, key 3) and 129 (r=128, key 0)
        if (taps == 3 && tid < 8) {
            int top = tid >> 2;
            int h = top ? 129 : 0;
            int tg = top ? t0 + 128 : t0 - 1;
            int part = tid & 3;
            int slot = top ? part : ((part + 3) & 3);
            short8 v = {0, 0, 0, 0, 0, 0, 0, 0};
            if (tg >= 0 && tg < T)
                v = *(const short8*)(Xk + ((size_t)b * T + tg) * 512 + cl + part * 8);
            *(short8*)&Alds[h * 32 + slot * 8] = v;
        }
        __syncthreads();

        for (int tap = 0; tap < taps; tap++) {
            int aoff = ((quad + ((l15 + tap - row0) >> 1)) & 3) * 8;  // A-frag slot
            short8 af[4], bfr[4];
#pragma unroll
            for (int mi = 0; mi < 4; mi++)
                af[mi] = *(short8*)&Alds[(wm * 64 + mi * 16 + l15 + tap) * 32 + aoff];
#pragma unroll
            for (int ni = 0; ni < 4; ni++)
                bfr[ni] = *(short8*)&Wlds[tap * 4096 + (wn * 64 + ni * 16 + l15) * 32 + wslot];
#pragma unroll
            for (int mi = 0; mi < 4; mi++)
#pragma unroll
                for (int ni = 0; ni < 4; ni++)
                    acc[mi][ni] = __builtin_amdgcn_mfma_f32_16x16x32_bf16(
                        af[mi], bfr[ni], acc[mi][ni], 0, 0, 0);
        }
    }

    // epilogue: affine + relu + bf16 store
    bf16* Yp; int colbase;
    if (blockIdx.x < ybsel) { Yp = Ya; colbase = co0; }
    else                    { Yp = Yb; colbase = co0 - 512; }
#pragma unroll
    for (int ni = 0; ni < 4; ni++) {
        int gcol = co0 + wn * 64 + ni * 16 + l15;
        int lcol = colbase + wn * 64 + ni * 16 + l15;
        float s = aff[gcol], bb = aff[CoutTot + gcol];
#pragma unroll
        for (int mi = 0; mi < 4; mi++) {
#pragma unroll
            for (int r = 0; r < 4; r++) {
                int row = t0 + wm * 64 + mi * 16 + quad * 4 + r;
                float y = acc[mi][ni][r] * s + bb;
                if (relu) y = fmaxf(y, 0.f);
                Yp[((size_t)b * T + row) * ystride + lcol] = __float2bfloat16(y);
            }
        }
    }
}

// ---------------- tiny-Cout conv heads ----------------
template<int CPL, int TAPS, int COUT, int MODE>
__global__ __launch_bounds__(256) void head_conv(
    const bf16* __restrict__ X, int T, int xstride, int xcol,
    const float* __restrict__ w, const float* __restrict__ bias,
    const float* __restrict__ scale_ptr, float* __restrict__ out)
{
    constexpr int RW = 16;
    constexpr int Cin = CPL * 64;
    int lane = threadIdx.x & 63, wv = threadIdx.x >> 6;
    int r0 = (blockIdx.x * 4 + wv) * RW;
    int b = r0 / T, t0 = r0 - b * T;
    const bf16* base = X + (size_t)b * T * xstride + xcol + lane * CPL;

    float wr[COUT][TAPS][CPL];
#pragma unroll
    for (int co = 0; co < COUT; co++)
#pragma unroll
        for (int k = 0; k < TAPS; k++)
#pragma unroll
            for (int j = 0; j < CPL; j++)
                wr[co][k][j] = w[((size_t)co * Cin + lane * CPL + j) * TAPS + k];
    float bia[COUT];
#pragma unroll
    for (int co = 0; co < COUT; co++) bia[co] = bias[co];
    float sc = MODE ? scale_ptr[0] : 0.f;

    float fprev[CPL], fcur[CPL], fnext[CPL];

    auto loadrow = [&](int t, float* f) {
        if (t < 0 || t >= T) {
#pragma unroll
            for (int j = 0; j < CPL; j++) f[j] = 0.f;
            return;
        }
        const short* p = (const short*)(base + (size_t)t * xstride);
        if constexpr (CPL == 8) {
            short8 v = *(const short8*)p;
#pragma unroll
            for (int j = 0; j < 8; j++)
                f[j] = __uint_as_float(((unsigned)(unsigned short)v[j]) << 16);
        } else {
            short4v v = *(const short4v*)p;
#pragma unroll
            for (int j = 0; j < CPL; j++)
                f[j] = __uint_as_float(((unsigned)(unsigned short)v[j]) << 16);
        }
    };

    if constexpr (TAPS == 3) { loadrow(t0 - 1, fprev); loadrow(t0, fcur); }

    for (int i = 0; i < RW; i++) {
        int t = t0 + i;
        float acc[COUT];
#pragma unroll
        for (int co = 0; co < COUT; co++) acc[co] = 0.f;
        if constexpr (TAPS == 3) {
            loadrow(t + 1, fnext);
#pragma unroll
            for (int co = 0; co < COUT; co++)
#pragma unroll
                for (int j = 0; j < CPL; j++)
                    acc[co] += fprev[j] * wr[co][0][j] + fcur[j] * wr[co][1][j]
                             + fnext[j] * wr[co][2][j];
#pragma unroll
            for (int j = 0; j < CPL; j++) { fprev[j] = fcur[j]; fcur[j] = fnext[j]; }
        } else {
            loadrow(t, fcur);
#pragma unroll
            for (int co = 0; co < COUT; co++)
#pragma unroll
                for (int j = 0; j < CPL; j++)
                    acc[co] += fcur[j] * wr[co][0][j];
        }
#pragma unroll
        for (int co = 0; co < COUT; co++)
#pragma unroll
            for (int off = 32; off; off >>= 1)
                acc[co] += __shfl_down(acc[co], off);
        if (lane == 0) {
#pragma unroll
            for (int co = 0; co < COUT; co++) {
                float v = acc[co] + bia[co];
                if (MODE) v = expf(v * sc);
                out[((size_t)b * COUT + co) * T + t] = v;
            }
        }
    }
}

// ---------------- launch ----------------
extern "C" void kernel_launch(void* const* d_in, const int* in_sizes, int n_in,
                              void* d_out, int out_size, void* d_ws, size_t ws_size,
                              hipStream_t stream) {
    const float* xin[3] = {(const float*)d_in[0], (const float*)d_in[1], (const float*)d_in[2]};
    const float* cls_w  = (const float*)d_in[3];
    const float* cls_b  = (const float*)d_in[4];
    const float* cls_g  = (const float*)d_in[5];
    const float* cls_be = (const float*)d_in[6];
    const float* cls_m  = (const float*)d_in[7];
    const float* cls_v  = (const float*)d_in[8];
    const float* box_w  = (const float*)d_in[9];
    const float* box_b  = (const float*)d_in[10];
    const float* box_g  = (const float*)d_in[11];
    const float* box_be = (const float*)d_in[12];
    const float* box_m  = (const float*)d_in[13];
    const float* box_v  = (const float*)d_in[14];
    const float* logits_w = (const float*)d_in[15];
    const float* logits_b = (const float*)d_in[16];
    const float* pred_w   = (const float*)d_in[17];
    const float* pred_b   = (const float*)d_in[18];
    const float* scales   = (const float*)d_in[19];
    const float* mix_w  = (const float*)d_in[20];
    const float* mix_b  = (const float*)d_in[21];
    const float* mix_g  = (const float*)d_in[22];
    const float* mix_be = (const float*)d_in[23];
    const float* mix_m  = (const float*)d_in[24];
    const float* mix_v  = (const float*)d_in[25];
    const float* iou_w1 = (const float*)d_in[26];
    const float* iou_b1 = (const float*)d_in[27];
    const float* iou_g  = (const float*)d_in[28];
    const float* iou_be = (const float*)d_in[29];
    const float* iou_m  = (const float*)d_in[30];
    const float* iou_v  = (const float*)d_in[31];
    const float* iou_w2 = (const float*)d_in[32];
    const float* iou_b2 = (const float*)d_in[33];

    float* out = (float*)d_out;
    char* ws = (char*)d_ws;
    bf16* B0   = (bf16*)(ws + OFF_B0);
    bf16* B1   = (bf16*)(ws + OFF_B1);
    bf16* B2   = (bf16*)(ws + OFF_B2);
    bf16* B3   = (bf16*)(ws + OFF_B3);
    bf16* W1   = (bf16*)(ws + OFF_W1);
    bf16* W2   = (bf16*)(ws + OFF_W2);
    bf16* WMIX = (bf16*)(ws + OFF_WMIX);
    bf16* WIOU = (bf16*)(ws + OFF_WIOU);
    float* AFF = (float*)(ws + OFF_AFF);
    // AFF: AFF1 @0 (2048), AFF2 @2048 (2048), AFFM @4096 (1024), AFFI @5120 (512)

    const int BIG = 1 << 30;
    const int WL = 512 * 512 * 3;   // fp32 elems per tower layer weight

    // ---- prep ----
    {
        int n = 512 * 512 * 3, g = (n + 255) / 256;
        wtrans<<<g, 256, 0, stream>>>(cls_w,      W1, 512, 512, 3, 1024, 0);
        wtrans<<<g, 256, 0, stream>>>(box_w,      W1, 512, 512, 3, 1024, 512);
        wtrans<<<g, 256, 0, stream>>>(cls_w + WL, W2, 512, 512, 3, 1024, 0);
        wtrans<<<g, 256, 0, stream>>>(box_w + WL, W2, 512, 512, 3, 1024, 512);
        int n2 = 512 * 1024;
        wtrans<<<(n2 + 255) / 256, 256, 0, stream>>>(mix_w, WMIX, 512, 1024, 1, 512, 0);
        int n3 = 256 * 512 * 3;
        wtrans<<<(n3 + 255) / 256, 256, 0, stream>>>(iou_w1, WIOU, 256, 512, 3, 256, 0);

        mkaff<<<2, 256, 0, stream>>>(cls_g,       cls_be,       cls_m,       cls_v,       cls_b,       AFF + 0,          512, 1024);
        mkaff<<<2, 256, 0, stream>>>(box_g,       box_be,       box_m,       box_v,       box_b,       AFF + 512,        512, 1024);
        mkaff<<<2, 256, 0, stream>>>(cls_g + 512, cls_be + 512, cls_m + 512, cls_v + 512, cls_b + 512, AFF + 2048,       512, 1024);
        mkaff<<<2, 256, 0, stream>>>(box_g + 512, box_be + 512, box_m + 512, box_v + 512, box_b + 512, AFF + 2048 + 512, 512, 1024);
        mkaff<<<2, 256, 0, stream>>>(mix_g, mix_be, mix_m, mix_v, mix_b,  AFF + 4096, 512, 512);
        mkaff<<<1, 256, 0, stream>>>(iou_g, iou_be, iou_m, iou_v, iou_b1, AFF + 5120, 256, 256);

        locs_k<<<7, 256, 0, stream>>>(out + 229376);
    }

    const int Ts[3] = {1024, 512, 256};
    const int LOGITS_OFF[3] = {0, 32768, 49152};
    const int BBOX_OFF[3]   = {57344, 122880, 155648};
    const int IOU_OFF[3]    = {172032, 204800, 221184};

    for (int lvl = 0; lvl < 3; lvl++) {
        int T = Ts[lvl];
        bf16* H = B2;  // iou hidden aliases B2 (dead by then), stride 256

        transpose_cvt<<<dim3(T / 32, 16, 32), dim3(32, 8), 0, stream>>>(xin[lvl], B0, T);

        // layer1: cls1+box1 merged. X=B0 -> Ya=B1 (cls1), Yb=B2 (box1)
        conv_mfma<<<dim3(8, T / 128, 32), 256, 0, stream>>>(
            B0, B0, 8, B0, BIG, T, 512, W1, 3, 1024, AFF + 0, B1, B2, 4, 512, 1);
        // layer2: cls2+box2 merged. Xa=B1 (bx<4), Xb=B2 -> Ya=B3 (cls2), Yb=B0 (box2)
        conv_mfma<<<dim3(8, T / 128, 32), 256, 0, stream>>>(
            B1, B2, 4, B1, BIG, T, 512, W2, 3, 1024, AFF + 2048, B3, B0, 4, 512, 1);

        // heads: logits on cls2 (B3), pred on box2 (B0)
        head_conv<8, 3, 1, 0><<<T / 2, 256, 0, stream>>>(
            B3, T, 512, 0, logits_w, logits_b, scales, out + LOGITS_OFF[lvl]);
        head_conv<8, 3, 2, 1><<<T / 2, 256, 0, stream>>>(
            B0, T, 512, 0, pred_w, pred_b, scales + lvl, out + BBOX_OFF[lvl]);

        // mix (k=1, Cin=1024: ci<512 from B3, ci>=512 from B0) -> B1
        conv_mfma<<<dim3(4, T / 128, 32), 256, 0, stream>>>(
            B3, B3, 8, B0, 512, T, 1024, WMIX, 1, 512, AFF + 4096, B1, B1, 8, 512, 1);
        // iou tower (512->256, k=3): B1 -> H (stride 256)
        conv_mfma<<<dim3(2, T / 128, 32), 256, 0, stream>>>(
            B1, B1, 8, B1, BIG, T, 512, WIOU, 3, 256, AFF + 5120, H, H, 8, 256, 1);
        // iou head (256->1, k=1)
        head_conv<4, 1, 1, 0><<<T / 2, 256, 0, stream>>>(
            H, T, 256, 0, iou_w2, iou_b2, scales, out + IOU_OFF[lvl]);
    }
}

// Round 5
// 770.702 us; speedup vs baseline: 2.8276x; 1.2263x over previous
//
#include <hip/hip_runtime.h>
#include <hip/hip_bf16.h>

typedef __hip_bfloat16 bf16;
typedef __attribute__((ext_vector_type(8))) short short8;
typedef __attribute__((ext_vector_type(4))) short short4v;
typedef __attribute__((ext_vector_type(4))) float float4v;

// ---------------- workspace layout (bf16 elements) ----------------
// EL0 = elements of a [32][1024][512] buffer; L1 = EL0/2, L2 = EL0/4.
#define EL0 16777216ull
// ws: A role (3 levels), B role (3 levels), D_L0, weights, AFF
#define E_A0 0ull
#define E_A1 (E_A0 + EL0)
#define E_A2 (E_A1 + EL0/2)
#define E_B0 (E_A2 + EL0/4)
#define E_B1 (E_B0 + EL0)
#define E_B2 (E_B1 + EL0/2)
#define E_D0 (E_B2 + EL0/4)
#define E_W1 (E_D0 + EL0)               // [3][1024][512]
#define E_W2 (E_W1 + 3ull*1024*512)
#define E_WMIX (E_W2 + 3ull*1024*512)   // [1][512][1024]
#define E_WIOU (E_WMIX + 512ull*1024)   // [3][256][512]
#define E_AFF  (E_WIOU + 3ull*256*512)  // floats after this (2B-elem offset is even)
// C role lives in d_in[0] (x0, 67.1MB); D_L1/D_L2 live in d_in[1] (x1, 33.5MB).
// Both are dead after the transpose stage and restored by the harness pre-launch.

// async global->LDS, 16B per lane; lds base must be wave-uniform
__device__ __forceinline__ void gl2lds16(const bf16* g, short* l) {
    __builtin_amdgcn_global_load_lds(
        (const __attribute__((address_space(1))) unsigned int*)g,
        (__attribute__((address_space(3))) unsigned int*)l, 16, 0, 0);
}

// ---------------- pointer-table structs ----------------
struct ConvP { const bf16* xa[3]; const bf16* xb[3]; const bf16* xc[3];
               bf16* ya[3]; bf16* yb[3]; };
struct HeadP { const bf16* x[3]; float* out[3]; };
struct TransP { const float* x[3]; bf16* y[3]; };
struct WSeg { const float* src; bf16* dst; int Co, Ci, K, CoTot, coOff; };
struct WP { WSeg s[6]; };
struct ASeg { const float* g; const float* be; const float* m; const float* v;
              const float* cb; float* out; int C, S; };
struct AP { ASeg s[6]; };

// ---------------- prep kernels (fused) ----------------
__global__ void wtrans_all(WP p) {
    WSeg s = p.s[blockIdx.y];
    long long n = (long long)s.Co * s.Ci * s.K;
    long long idx = (long long)blockIdx.x * 256 + threadIdx.x;
    if (idx >= n) return;
    int ci = (int)(idx % s.Ci);
    long long r = idx / s.Ci;
    int co = (int)(r % s.Co);
    int k  = (int)(r / s.Co);
    s.dst[((size_t)k * s.CoTot + s.coOff + co) * s.Ci + ci] =
        __float2bfloat16(s.src[((long long)co * s.Ci + ci) * s.K + k]);
}

__global__ void mkaff_all(AP p) {
    ASeg s = p.s[blockIdx.y];
    int i = blockIdx.x * 256 + threadIdx.x;
    if (i >= s.C) return;
    float sc = s.g[i] * rsqrtf(s.v[i] + 1e-5f);
    s.out[i] = sc;
    s.out[s.S + i] = s.cb[i] * sc + s.be[i] - s.m[i] * sc;
}

// x [B][512][T] fp32 -> xb [B][T][512] bf16, all levels in one dispatch
__global__ void transpose_cvt(TransP p) {
    __shared__ float tile[32][33];
    int tx = blockIdx.x;
    int lvl = (tx >= 48) ? 2 : (tx >= 32) ? 1 : 0;
    int base = (lvl == 2) ? 48 : (lvl == 1) ? 32 : 0;
    int T = 1024 >> lvl;
    int t0 = (tx - base) * 32, c0 = blockIdx.y * 32, b = blockIdx.z;
    const float* xp = p.x[lvl] + ((size_t)b * 512 + c0) * T + t0;
    for (int i = 0; i < 4; i++) {
        int c = threadIdx.y + i * 8;
        tile[c][threadIdx.x] = xp[(size_t)c * T + threadIdx.x];
    }
    __syncthreads();
    bf16* yp = p.y[lvl] + ((size_t)b * T + t0) * 512 + c0;
    for (int i = 0; i < 4; i++) {
        int t = threadIdx.y + i * 8;
        yp[(size_t)t * 512 + threadIdx.x] = __float2bfloat16(tile[threadIdx.x][t]);
    }
}

__global__ void locs_k(float* __restrict__ out) {
    int i = blockIdx.x * 256 + threadIdx.x;
    if (i < 1024)      out[i] = (float)i + 0.5f;
    else if (i < 1536) out[i] = (float)(i - 1024) * 2.0f + 1.0f;
    else if (i < 1792) out[i] = (float)(i - 1536) * 4.0f + 2.0f;
}

// ---------------- main MFMA conv, all levels fused ----------------
// grid.y = 14 tiles (L0:0-7, L1:8-11, L2:12-13). Per level: X select by bx<xbsel
// (Xa/Xb); ci>=xsplit -> Xc. Y: bx<ybsel -> Ya@co0 else Yb@co0-512, stride ystride.
// LDS bank swizzle: slot permutation keyed on (row>>1)&3 (R4, conflicts=0).
__global__ __launch_bounds__(256, 4) void conv_mfma(
    ConvP p, int xbsel, int xsplit, int Cin,
    const bf16* __restrict__ Wt, int taps, int CoutTot,
    const float* __restrict__ aff,
    int ybsel, int ystride, int relu)
{
    __shared__ short Alds[130 * 32];
    __shared__ short Wlds[3 * 128 * 32];

    int gy = blockIdx.y;
    int lvl = (gy >= 12) ? 2 : (gy >= 8) ? 1 : 0;
    int tb  = (lvl == 2) ? 12 : (lvl == 1) ? 8 : 0;
    int T = 1024 >> lvl;
    int t0 = (gy - tb) * 128;

    int co0 = blockIdx.x * 128, b = blockIdx.z;
    int tid = threadIdx.x;
    int lane = tid & 63, wv = tid >> 6;
    int wm = wv >> 1, wn = wv & 1;
    int quad = lane >> 4, l15 = lane & 15;
    int lr = lane >> 2, lp = lane & 3;

    const bf16* X0 = (blockIdx.x < xbsel) ? p.xa[lvl] : p.xb[lvl];
    const bf16* Xc = p.xc[lvl];

    float4v acc[4][4] = {};

    int kIters = Cin >> 5;
    int row0 = (taps == 3) ? 1 : 0;

    int pg = (lp - (lr >> 1)) & 3;
    int wslot = ((quad + (l15 >> 1)) & 3) * 8;

    for (int kk = 0; kk < kIters; kk++) {
        int ci0 = kk << 5;
        const bf16* Xk; int cl;
        if (ci0 < xsplit) { Xk = X0; cl = ci0; } else { Xk = Xc; cl = ci0 - xsplit; }
        if (kk) __syncthreads();

        for (int inst = wv; inst < 8; inst += 4) {
            int row = inst * 16 + lr;
            const bf16* g = Xk + ((size_t)b * T + t0 + row) * 512 + cl + pg * 8;
            gl2lds16(g, &Alds[(row0 + inst * 16) * 32]);
        }
        for (int inst = wv; inst < taps * 8; inst += 4) {
            int tap = inst >> 3, i2 = inst & 7;
            int row = i2 * 16 + lr;
            const bf16* g = Wt + ((size_t)tap * CoutTot + co0 + row) * Cin + ci0 + pg * 8;
            gl2lds16(g, &Wlds[tap * 4096 + i2 * 512]);
        }
        if (taps == 3 && tid < 8) {
            int top = tid >> 2;
            int h = top ? 129 : 0;
            int tg = top ? t0 + 128 : t0 - 1;
            int part = tid & 3;
            int slot = top ? part : ((part + 3) & 3);
            short8 v = {0, 0, 0, 0, 0, 0, 0, 0};
            if (tg >= 0 && tg < T)
                v = *(const short8*)(Xk + ((size_t)b * T + tg) * 512 + cl + part * 8);
            *(short8*)&Alds[h * 32 + slot * 8] = v;
        }
        __syncthreads();

        for (int tap = 0; tap < taps; tap++) {
            int aoff = ((quad + ((l15 + tap - row0) >> 1)) & 3) * 8;
            short8 af[4], bfr[4];
#pragma unroll
            for (int mi = 0; mi < 4; mi++)
                af[mi] = *(short8*)&Alds[(wm * 64 + mi * 16 + l15 + tap) * 32 + aoff];
#pragma unroll
            for (int ni = 0; ni < 4; ni++)
                bfr[ni] = *(short8*)&Wlds[tap * 4096 + (wn * 64 + ni * 16 + l15) * 32 + wslot];
#pragma unroll
            for (int mi = 0; mi < 4; mi++)
#pragma unroll
                for (int ni = 0; ni < 4; ni++)
                    acc[mi][ni] = __builtin_amdgcn_mfma_f32_16x16x32_bf16(
                        af[mi], bfr[ni], acc[mi][ni], 0, 0, 0);
        }
    }

    bf16* Yp; int colbase;
    if (blockIdx.x < ybsel) { Yp = p.ya[lvl]; colbase = co0; }
    else                    { Yp = p.yb[lvl]; colbase = co0 - 512; }
#pragma unroll
    for (int ni = 0; ni < 4; ni++) {
        int gcol = co0 + wn * 64 + ni * 16 + l15;
        int lcol = colbase + wn * 64 + ni * 16 + l15;
        float s = aff[gcol], bb = aff[CoutTot + gcol];
#pragma unroll
        for (int mi = 0; mi < 4; mi++) {
#pragma unroll
            for (int r = 0; r < 4; r++) {
                int row = t0 + wm * 64 + mi * 16 + quad * 4 + r;
                float y = acc[mi][ni][r] * s + bb;
                if (relu) y = fmaxf(y, 0.f);
                Yp[((size_t)b * T + row) * ystride + lcol] = __float2bfloat16(y);
            }
        }
    }
}

// ---------------- tiny-Cout conv heads, all levels fused ----------------
// block = 4 waves x 16 rows = 64 rows. Level block bases: {0, 512, 768}.
template<int CPL, int TAPS, int COUT, int MODE>
__global__ __launch_bounds__(256) void head_conv(
    HeadP p, int xstride,
    const float* __restrict__ w, const float* __restrict__ bias,
    const float* __restrict__ scale_ptr)
{
    constexpr int RW = 16;
    constexpr int Cin = CPL * 64;
    int bid = blockIdx.x;
    int lvl = (bid >= 768) ? 2 : (bid >= 512) ? 1 : 0;
    int bbase = (lvl == 2) ? 768 : (lvl == 1) ? 512 : 0;
    int T = 1024 >> lvl;
    int lane = threadIdx.x & 63, wv = threadIdx.x >> 6;
    int r0 = (bid - bbase) * 64 + wv * RW;
    int b = r0 / T, t0 = r0 - b * T;
    const bf16* base = p.x[lvl] + (size_t)b * T * xstride + lane * CPL;
    float* out = p.out[lvl];

    float wr[COUT][TAPS][CPL];
#pragma unroll
    for (int co = 0; co < COUT; co++)
#pragma unroll
        for (int k = 0; k < TAPS; k++)
#pragma unroll
            for (int j = 0; j < CPL; j++)
                wr[co][k][j] = w[((size_t)co * Cin + lane * CPL + j) * TAPS + k];
    float bia[COUT];
#pragma unroll
    for (int co = 0; co < COUT; co++) bia[co] = bias[co];
    float sc = MODE ? scale_ptr[lvl] : 0.f;

    float fprev[CPL], fcur[CPL], fnext[CPL];

    auto loadrow = [&](int t, float* f) {
        if (t < 0 || t >= T) {
#pragma unroll
            for (int j = 0; j < CPL; j++) f[j] = 0.f;
            return;
        }
        const short* q = (const short*)(base + (size_t)t * xstride);
        if constexpr (CPL == 8) {
            short8 v = *(const short8*)q;
#pragma unroll
            for (int j = 0; j < 8; j++)
                f[j] = __uint_as_float(((unsigned)(unsigned short)v[j]) << 16);
        } else {
            short4v v = *(const short4v*)q;
#pragma unroll
            for (int j = 0; j < CPL; j++)
                f[j] = __uint_as_float(((unsigned)(unsigned short)v[j]) << 16);
        }
    };

    if constexpr (TAPS == 3) { loadrow(t0 - 1, fprev); loadrow(t0, fcur); }

    for (int i = 0; i < RW; i++) {
        int t = t0 + i;
        float acc[COUT];
#pragma unroll
        for (int co = 0; co < COUT; co++) acc[co] = 0.f;
        if constexpr (TAPS == 3) {
            loadrow(t + 1, fnext);
#pragma unroll
            for (int co = 0; co < COUT; co++)
#pragma unroll
                for (int j = 0; j < CPL; j++)
                    acc[co] += fprev[j] * wr[co][0][j] + fcur[j] * wr[co][1][j]
                             + fnext[j] * wr[co][2][j];
#pragma unroll
            for (int j = 0; j < CPL; j++) { fprev[j] = fcur[j]; fcur[j] = fnext[j]; }
        } else {
            loadrow(t, fcur);
#pragma unroll
            for (int co = 0; co < COUT; co++)
#pragma unroll
                for (int j = 0; j < CPL; j++)
                    acc[co] += fcur[j] * wr[co][0][j];
        }
#pragma unroll
        for (int co = 0; co < COUT; co++)
#pragma unroll
            for (int off = 32; off; off >>= 1)
                acc[co] += __shfl_down(acc[co], off);
        if (lane == 0) {
#pragma unroll
            for (int co = 0; co < COUT; co++) {
                float v = acc[co] + bia[co];
                if (MODE) v = expf(v * sc);
                out[((size_t)b * COUT + co) * T + t] = v;
            }
        }
    }
}

// ---------------- launch ----------------
extern "C" void kernel_launch(void* const* d_in, const int* in_sizes, int n_in,
                              void* d_out, int out_size, void* d_ws, size_t ws_size,
                              hipStream_t stream) {
    const float* xin0 = (const float*)d_in[0];
    const float* xin1 = (const float*)d_in[1];
    const float* xin2 = (const float*)d_in[2];
    const float* cls_w  = (const float*)d_in[3];
    const float* cls_b  = (const float*)d_in[4];
    const float* cls_g  = (const float*)d_in[5];
    const float* cls_be = (const float*)d_in[6];
    const float* cls_m  = (const float*)d_in[7];
    const float* cls_v  = (const float*)d_in[8];
    const float* box_w  = (const float*)d_in[9];
    const float* box_b  = (const float*)d_in[10];
    const float* box_g  = (const float*)d_in[11];
    const float* box_be = (const float*)d_in[12];
    const float* box_m  = (const float*)d_in[13];
    const float* box_v  = (const float*)d_in[14];
    const float* logits_w = (const float*)d_in[15];
    const float* logits_b = (const float*)d_in[16];
    const float* pred_w   = (const float*)d_in[17];
    const float* pred_b   = (const float*)d_in[18];
    const float* scales   = (const float*)d_in[19];
    const float* mix_w  = (const float*)d_in[20];
    const float* mix_b  = (const float*)d_in[21];
    const float* mix_g  = (const float*)d_in[22];
    const float* mix_be = (const float*)d_in[23];
    const float* mix_m  = (const float*)d_in[24];
    const float* mix_v  = (const float*)d_in[25];
    const float* iou_w1 = (const float*)d_in[26];
    const float* iou_b1 = (const float*)d_in[27];
    const float* iou_g  = (const float*)d_in[28];
    const float* iou_be = (const float*)d_in[29];
    const float* iou_m  = (const float*)d_in[30];
    const float* iou_v  = (const float*)d_in[31];
    const float* iou_w2 = (const float*)d_in[32];
    const float* iou_b2 = (const float*)d_in[33];

    float* out = (float*)d_out;
    bf16* wsb = (bf16*)d_ws;

    // roles: A,B in ws; C in x0; D_L0 in ws, D_L1/L2 in x1 (inputs dead after transpose)
    bf16* A[3] = { wsb + E_A0, wsb + E_A1, wsb + E_A2 };
    bf16* Bb[3] = { wsb + E_B0, wsb + E_B1, wsb + E_B2 };
    bf16* C[3] = { (bf16*)xin0, (bf16*)xin0 + EL0, (bf16*)xin0 + EL0 + EL0/2 };
    bf16* D[3] = { wsb + E_D0, (bf16*)xin1, (bf16*)xin1 + EL0/2 };
    bf16* W1   = wsb + E_W1;
    bf16* W2   = wsb + E_W2;
    bf16* WMIX = wsb + E_WMIX;
    bf16* WIOU = wsb + E_WIOU;
    float* AFF = (float*)(wsb + E_AFF);
    // AFF: cls1@0, box1@512 (S=1024); cls2@2048, box2@2048+512; mix@4096; iou@5120

    const int BIG = 1 << 30;
    const int WL = 512 * 512 * 3;

    // ---- prep (3 dispatches) ----
    {
        WP wp;
        wp.s[0] = { cls_w,      W1, 512, 512, 3, 1024, 0 };
        wp.s[1] = { box_w,      W1, 512, 512, 3, 1024, 512 };
        wp.s[2] = { cls_w + WL, W2, 512, 512, 3, 1024, 0 };
        wp.s[3] = { box_w + WL, W2, 512, 512, 3, 1024, 512 };
        wp.s[4] = { mix_w,  WMIX, 512, 1024, 1, 512, 0 };
        wp.s[5] = { iou_w1, WIOU, 256, 512, 3, 256, 0 };
        wtrans_all<<<dim3(3072, 6), 256, 0, stream>>>(wp);

        AP ap;
        ap.s[0] = { cls_g,       cls_be,       cls_m,       cls_v,       cls_b,       AFF + 0,          512, 1024 };
        ap.s[1] = { box_g,       box_be,       box_m,       box_v,       box_b,       AFF + 512,        512, 1024 };
        ap.s[2] = { cls_g + 512, cls_be + 512, cls_m + 512, cls_v + 512, cls_b + 512, AFF + 2048,       512, 1024 };
        ap.s[3] = { box_g + 512, box_be + 512, box_m + 512, box_v + 512, box_b + 512, AFF + 2048 + 512, 512, 1024 };
        ap.s[4] = { mix_g, mix_be, mix_m, mix_v, mix_b,  AFF + 4096, 512, 512 };
        ap.s[5] = { iou_g, iou_be, iou_m, iou_v, iou_b1, AFF + 5120, 256, 256 };
        mkaff_all<<<dim3(2, 6), 256, 0, stream>>>(ap);

        locs_k<<<7, 256, 0, stream>>>(out + 229376);
    }

    float* LOG[3] = { out + 0,      out + 32768,  out + 49152 };
    float* BBX[3] = { out + 57344,  out + 122880, out + 155648 };
    float* IOU[3] = { out + 172032, out + 204800, out + 221184 };

    // ---- transpose all levels -> A ----
    {
        TransP tp;
        tp.x[0] = xin0; tp.x[1] = xin1; tp.x[2] = xin2;
        tp.y[0] = A[0]; tp.y[1] = A[1]; tp.y[2] = A[2];
        transpose_cvt<<<dim3(56, 16, 32), dim3(32, 8), 0, stream>>>(tp);
    }

    // ---- tower layer1 (cls1||box1): A -> B(cls1), C(box1) ----
    {
        ConvP cp;
        for (int l = 0; l < 3; l++) {
            cp.xa[l] = A[l]; cp.xb[l] = A[l]; cp.xc[l] = A[l];
            cp.ya[l] = Bb[l]; cp.yb[l] = C[l];
        }
        conv_mfma<<<dim3(8, 14, 32), 256, 0, stream>>>(
            cp, 8, BIG, 512, W1, 3, 1024, AFF + 0, 4, 512, 1);
    }
    // ---- tower layer2: B(cls1),C(box1) -> D(cls2), A(box2) ----
    {
        ConvP cp;
        for (int l = 0; l < 3; l++) {
            cp.xa[l] = Bb[l]; cp.xb[l] = C[l]; cp.xc[l] = Bb[l];
            cp.ya[l] = D[l]; cp.yb[l] = A[l];
        }
        conv_mfma<<<dim3(8, 14, 32), 256, 0, stream>>>(
            cp, 4, BIG, 512, W2, 3, 1024, AFF + 2048, 4, 512, 1);
    }
    // ---- heads: logits on cls2 (D), pred on box2 (A) ----
    {
        HeadP hp;
        for (int l = 0; l < 3; l++) { hp.x[l] = D[l]; hp.out[l] = LOG[l]; }
        head_conv<8, 3, 1, 0><<<896, 256, 0, stream>>>(hp, 512, logits_w, logits_b, scales);
        HeadP hp2;
        for (int l = 0; l < 3; l++) { hp2.x[l] = A[l]; hp2.out[l] = BBX[l]; }
        head_conv<8, 3, 2, 1><<<896, 256, 0, stream>>>(hp2, 512, pred_w, pred_b, scales);
    }
    // ---- mix (k=1, Cin=1024: D || A) -> B ----
    {
        ConvP cp;
        for (int l = 0; l < 3; l++) {
            cp.xa[l] = D[l]; cp.xb[l] = D[l]; cp.xc[l] = A[l];
            cp.ya[l] = Bb[l]; cp.yb[l] = Bb[l];
        }
        conv_mfma<<<dim3(4, 14, 32), 256, 0, stream>>>(
            cp, 8, 512, 1024, WMIX, 1, 512, AFF + 4096, 8, 512, 1);
    }
    // ---- iou tower (512->256, k=3): B -> C (stride 256) ----
    {
        ConvP cp;
        for (int l = 0; l < 3; l++) {
            cp.xa[l] = Bb[l]; cp.xb[l] = Bb[l]; cp.xc[l] = Bb[l];
            cp.ya[l] = C[l]; cp.yb[l] = C[l];
        }
        conv_mfma<<<dim3(2, 14, 32), 256, 0, stream>>>(
            cp, 8, BIG, 512, WIOU, 3, 256, AFF + 5120, 8, 256, 1);
    }
    // ---- iou head (256->1, k=1) on C ----
    {
        HeadP hp;
        for (int l = 0; l < 3; l++) { hp.x[l] = C[l]; hp.out[l] = IOU[l]; }
        head_conv<4, 1, 1, 0><<<896, 256, 0, stream>>>(hp, 256, iou_w2, iou_b2, scales);
    }
}